// Round 5
// baseline (237.873 us; speedup 1.0000x reference)
//
#include <hip/hip_runtime.h>

// Problem constants
#define BB 4
#define TT 2048
#define CC 1024
#define C3 3072
#define HH 16
#define HD 64
#define BT 8192   // BB*TT

// Linear TS=32 (R1: padding regressed; gload_lds REQUIRES linear dest anyway).
#define TS 32
#define TSZ (64 * TS)   // u16 elements per 64-row sub-tile (4 KB)

typedef __bf16 bf16x8 __attribute__((ext_vector_type(8)));
typedef float floatx4 __attribute__((ext_vector_type(4)));
typedef unsigned uintx2 __attribute__((ext_vector_type(2)));
typedef unsigned short u16;

__device__ __forceinline__ u16 f2bf(float f) {
  union { float f; unsigned u; } a; a.f = f;
  return (u16)((a.u + 0x7fffu + ((a.u >> 16) & 1u)) >> 16);  // RNE
}
__device__ __forceinline__ bf16x8 ld8(const u16* p) { return *(const bf16x8*)p; }
__device__ __forceinline__ floatx4 mfma16(bf16x8 a, bf16x8 b, floatx4 c) {
  return __builtin_amdgcn_mfma_f32_16x16x32_bf16(a, b, c, 0, 0, 0);
}

// Async global->LDS, 16B/lane. LDS dest = wave-uniform base + lane*16 (m104);
// global src is per-lane. Drained by the s_waitcnt vmcnt(0) the compiler
// emits before s_barrier (__syncthreads).
__device__ __forceinline__ void gload16(const u16* g, u16* l) {
  __builtin_amdgcn_global_load_lds(
      (const __attribute__((address_space(1))) void*)g,
      (__attribute__((address_space(3))) void*)l, 16, 0, 0);
}

// qd-group redistribution via permlane32/16_swap (gfx950):
//   chain: r0 = [a@0, a@2, b@0, b@2], r1 = [a@1, a@3, b@1, b@3]  (by qd group)
// = the PV A-frag word routing (verified in R3).
__device__ __forceinline__ void qd_xchg(unsigned a, unsigned b,
                                        unsigned& r0, unsigned& r1) {
  uintx2 t = __builtin_amdgcn_permlane32_swap(a, b, false, false);
  uintx2 r = __builtin_amdgcn_permlane16_swap(t[0], t[1], false, false);
  r0 = r[0]; r1 = r[1];
}

// ---------------------------------------------------------------------------
// fp32 -> bf16 elementwise (for x)
// ---------------------------------------------------------------------------
__global__ __launch_bounds__(256) void tobf16_kernel(const float4* __restrict__ src,
                                                     ushort4* __restrict__ dst, int n4) {
  int i = blockIdx.x * 256 + threadIdx.x;
  if (i >= n4) return;
  float4 v = src[i];
  ushort4 o; o.x = f2bf(v.x); o.y = f2bf(v.y); o.z = f2bf(v.z); o.w = f2bf(v.w);
  dst[i] = o;
}

// ---------------------------------------------------------------------------
// fp32 [K][N] -> bf16 [N][K] transpose (LDS-tiled, 64x64 tiles)
// ---------------------------------------------------------------------------
__global__ __launch_bounds__(256) void transpose_bf16_kernel(const float* __restrict__ src,
                                                             u16* __restrict__ dst,
                                                             int K, int N) {
  __shared__ float s[64][65];
  const int t = threadIdx.x;
  const int r = t >> 4;           // 0..15
  const int c = (t & 15) * 4;     // 0..60
  const int k0 = blockIdx.y * 64, n0 = blockIdx.x * 64;
#pragma unroll
  for (int i = 0; i < 4; ++i) {
    float4 v = *(const float4*)&src[(size_t)(k0 + r + i * 16) * N + n0 + c];
    s[r + i * 16][c + 0] = v.x; s[r + i * 16][c + 1] = v.y;
    s[r + i * 16][c + 2] = v.z; s[r + i * 16][c + 3] = v.w;
  }
  __syncthreads();
#pragma unroll
  for (int i = 0; i < 4; ++i) {
    const int nn = r + i * 16;
    ushort4 o;
    o.x = f2bf(s[c + 0][nn]); o.y = f2bf(s[c + 1][nn]);
    o.z = f2bf(s[c + 2][nn]); o.w = f2bf(s[c + 3][nn]);
    *(ushort4*)&dst[(size_t)(n0 + nn) * K + k0 + c] = o;
  }
}

// ---------------------------------------------------------------------------
// GEMM: C[M,N] = A[M,K] @ B^T[N,K], 128x128 tile, BK=32, 256 thr = 4 waves.
// global_load_lds staging (async DMA); one barrier per K-iter (R4, verified).
// MODE 1: qkv epilogue via LDS bounce -> coalesced stores.  Q columns
//         (n0 < CC) PRE-SCALED by 0.125*log2(e) before the bf16 rounding.
// MODE 2: fp32 out + bias, direct stores
// ---------------------------------------------------------------------------
template<int MODE>
__global__ __launch_bounds__(256) void gemm_kernel(
    const u16* __restrict__ A, const u16* __restrict__ B,
    const float* __restrict__ bias, float* __restrict__ outf,
    u16* __restrict__ qk, u16* __restrict__ vT,
    int M, int N, int K) {
  __shared__ u16 smem[2][2][2 * TSZ];   // [buf][A|B][128 rows x TS] = 32 KB

  const int t = threadIdx.x;
  const int w = t >> 6, lane = t & 63, lr = lane & 15, qd = lane >> 4;
  const int wm = w >> 1, wn = w & 1;
  const int m0 = blockIdx.y * 128, n0 = blockIdx.x * 128;

  // Staging geometry: thread t covers 16B at row sr=t>>2, col sc=(t&3)*8 of a
  // 64x32 half-tile -> u16 offset t*8 (lane-linear; wave base wb = w*512).
  const int sr = t >> 2;
  const int sc = (t & 3) * 8;
  const int wb = (t & ~63) * 8;
  const u16* Ag = A + (size_t)(m0 + sr) * K + sc;
  const u16* Bg = B + (size_t)(n0 + sr) * K + sc;

  floatx4 acc[4][4] = {};

  {  // prologue: stage tile 0 into buf 0
    u16* sA = &smem[0][0][0];
    u16* sB = &smem[0][1][0];
    gload16(Ag,                  &sA[wb]);
    gload16(Ag + (size_t)64 * K, &sA[TSZ + wb]);
    gload16(Bg,                  &sB[wb]);
    gload16(Bg + (size_t)64 * K, &sB[TSZ + wb]);
  }
  __syncthreads();

  for (int k0 = 0; k0 < K; k0 += 32) {
    const int p = (k0 >> 5) & 1;
    if (k0 + 32 < K) {               // stage next tile into the OTHER buffer
      u16* sA = &smem[p ^ 1][0][0];
      u16* sB = &smem[p ^ 1][1][0];
      gload16(Ag + k0 + 32,                  &sA[wb]);
      gload16(Ag + (size_t)64 * K + k0 + 32, &sA[TSZ + wb]);
      gload16(Bg + k0 + 32,                  &sB[wb]);
      gload16(Bg + (size_t)64 * K + k0 + 32, &sB[TSZ + wb]);
    }
    const u16* sA = &smem[p][0][0];
    const u16* sB = &smem[p][1][0];

    bf16x8 af[4], bf[4];
#pragma unroll
    for (int mj = 0; mj < 4; ++mj) af[mj] = ld8(&sA[(wm * 64 + mj * 16 + lr) * TS + qd * 8]);
#pragma unroll
    for (int nj = 0; nj < 4; ++nj) bf[nj] = ld8(&sB[(wn * 64 + nj * 16 + lr) * TS + qd * 8]);
#pragma unroll
    for (int mj = 0; mj < 4; ++mj)
#pragma unroll
      for (int nj = 0; nj < 4; ++nj)
        acc[mj][nj] = mfma16(af[mj], bf[nj], acc[mj][nj]);
    __syncthreads();   // drains next-tile stage (vmcnt0) + protects buf reuse
  }

  // Epilogue. D layout: col(N)=lane&15, row(M)=(lane>>4)*4+i  [m89/m91]
  const int rowg0 = m0 + wm * 64;
  const int colg0 = n0 + wn * 64;
  if constexpr (MODE == 2) {
#pragma unroll
    for (int nj = 0; nj < 4; ++nj) {
      const int col = colg0 + nj * 16 + lr;
      const float bv = bias[col];
#pragma unroll
      for (int mj = 0; mj < 4; ++mj)
#pragma unroll
        for (int i = 0; i < 4; ++i)
          outf[(size_t)(rowg0 + mj * 16 + qd * 4 + i) * N + col] = acc[mj][nj][i] + bv;
    }
  } else {
    // loop ended with a barrier; staging smem is free to reuse as bounce
    u16* Tw = &smem[0][0][0] + w * (32 * 72);
    const bool isV = (n0 >= 2 * CC);   // block-uniform
    if (!isV) {
      // Q pre-scale: fold softmax scale*log2(e) into Q (block-uniform select)
      const float qs = (n0 < CC) ? 0.18033688011f : 1.0f;
      // Q/K: row-major bounce, then 128B-coalesced row stores
#pragma unroll
      for (int half = 0; half < 2; ++half) {
#pragma unroll
        for (int m2 = 0; m2 < 2; ++m2)
#pragma unroll
          for (int nj = 0; nj < 4; ++nj)
#pragma unroll
            for (int i = 0; i < 4; ++i)
              Tw[(m2 * 16 + qd * 4 + i) * 72 + nj * 16 + lr] =
                  f2bf(acc[half * 2 + m2][nj][i] * qs);
#pragma unroll
        for (int s = 0; s < 4; ++s) {
          const int rl = s * 8 + (lane >> 3);
          const int c0 = (lane & 7) * 8;
          *(bf16x8*)&qk[(size_t)(rowg0 + half * 32 + rl) * (2 * CC) + colg0 + c0] =
              ld8(&Tw[rl * 72 + c0]);
        }
      }
    } else {
      // V: transpose bounce -> vT[b*1024 + dim][t], 128B-coalesced
      const int bI = m0 >> 11;
      const int tbase = (m0 & (TT - 1)) + wm * 64;
      const int dim0 = colg0 - 2 * CC;
#pragma unroll
      for (int half = 0; half < 2; ++half) {
#pragma unroll
        for (int n2 = 0; n2 < 2; ++n2)
#pragma unroll
          for (int mj = 0; mj < 4; ++mj)
#pragma unroll
            for (int i = 0; i < 4; ++i)
              Tw[(n2 * 16 + lr) * 72 + mj * 16 + qd * 4 + i] =
                  f2bf(acc[mj][half * 2 + n2][i]);
#pragma unroll
        for (int s = 0; s < 4; ++s) {
          const int dl = s * 8 + (lane >> 3);
          const int t0 = (lane & 7) * 8;
          *(bf16x8*)&vT[((size_t)(bI << 10) + dim0 + half * 32 + dl) * TT + tbase + t0] =
              ld8(&Tw[dl * 72 + t0]);
        }
      }
    }
  }
}

// ---------------------------------------------------------------------------
// Causal flash attention, fixed-max softmax.  Block = 64 q x 64-key tiles.
// R5: 2-WAY KEY SPLIT.  wave w -> (m2 = w>>1: q-half, ks = w&1: key-half).
// Each wave computes 32 q x 32 keys per k-tile (same score volume/wave as
// before) but reads HALF the K/V fragments: 8 ds_read_b128 -> 4+4.
// Per block-iter CU LDS traffic: 80 KB -> 48 KB (4x16KB frag reads -> 4x8KB).
//   QK^T: s[ms][ku] = K(ks-half,ku) . Q(ms)  -> P[key=ks*32+ku*16+qd*4+i]
//         [q = q0+m2*32+ms*16+lr]  (D: col=lr, row=qd*4+i)
//   P pack + qd_xchg (verified R3 algebra, W[ku=0],W[ku=1] per ms) -> pf[ms]
//         = A-frag P^T[q][key-window qd*8+e] over the wave's 32 keys.
//   PV:   o[ms][j] += pf[ms] . V[ks-half]  (K=32 over the wave's keys)
// End: pairwise (ks=1 -> ks=0) O/lsum reduction through LDS (reuses sKV).
// K/V staging via global_load_lds, one barrier per kt (R4, verified).
// Grid (x=bh, y=qtile): same-bh blocks share an XCD; qtile = 31-y: LPT.
// ---------------------------------------------------------------------------
__global__ __launch_bounds__(256, 4) void attn_kernel(const u16* __restrict__ qk,
                                                      const u16* __restrict__ vT,
                                                      u16* __restrict__ att) {
  __shared__ u16 sKV[2][4][TSZ];      // [buf][K0,K1,V0,V1] = 32768 B

  const int t = threadIdx.x;
  const int w = t >> 6, lane = t & 63, lr = lane & 15, qd = lane >> 4;
  const int m2 = w >> 1;              // q-half
  const int ks = w & 1;               // key-half
  const int qtile = 31 - blockIdx.y;  // LPT: longest first
  const int bh = blockIdx.x;          // x fastest -> XCD = bh % 8 for all qtiles
  const int b = bh >> 4, h = bh & 15;
  const int q0 = qtile * 64;
  const u16* qbase = qk + (size_t)b * TT * (2 * CC);

  // Q frags (B-operand), pre-scaled by 0.125*log2e: q = q0 + m2*32 + ms*16 + lr
  bf16x8 qf[2][2];
  int myq[2];
#pragma unroll
  for (int ms = 0; ms < 2; ++ms) {
    const int qrow = q0 + m2 * 32 + ms * 16 + lr;
    myq[ms] = qrow;
    const u16* qp = qbase + (size_t)qrow * (2 * CC) + h * HD;
    qf[ms][0] = ld8(qp + qd * 8);
    qf[ms][1] = ld8(qp + 32 + qd * 8);
  }

  const int sr = t >> 2, sc = (t & 3) * 8;
  const int wb = (t & ~63) * 8;   // wave-uniform u16 base within a sub-tile
  const u16* Kg = qbase + (size_t)sr * (2 * CC) + CC + h * HD + sc;
  const u16* Vg = vT + ((size_t)bh * HD + sr) * TT + sc;

  float lsum[2] = {0.f, 0.f};     // per (ms): partial over this wave's keys
  floatx4 o[2][4] = {};           // [ms][dim-block j]

  {  // prologue: stage tile 0 into buf 0
    u16* b0 = &sKV[0][0][0];
    gload16(Kg,      &b0[wb]);
    gload16(Kg + 32, &b0[TSZ + wb]);
    gload16(Vg,      &b0[2 * TSZ + wb]);
    gload16(Vg + 32, &b0[3 * TSZ + wb]);
  }
  __syncthreads();

  for (int kt = 0; kt <= qtile; ++kt) {
    if (kt < qtile) {               // stage kt+1 into the OTHER buffer
      const int kn = (kt + 1) * 64;
      u16* bn = &sKV[(kt + 1) & 1][0][0];
      gload16(Kg + (size_t)kn * (2 * CC),      &bn[wb]);
      gload16(Kg + (size_t)kn * (2 * CC) + 32, &bn[TSZ + wb]);
      gload16(Vg + kn,                         &bn[2 * TSZ + wb]);
      gload16(Vg + kn + 32,                    &bn[3 * TSZ + wb]);
    }

    const u16* sK0 = &sKV[kt & 1][0][0];   // [key 0..63][dim 0..31]
    const u16* sK1 = &sKV[kt & 1][1][0];   // [key 0..63][dim 32..63]
    const u16* sVk = &sKV[kt & 1][2 + ks][0];  // [dim 0..63][key ks*32..+31]

    // QK^T: s[ms][ku] -> S[key=kt*64+ks*32+ku*16+qd*4+i][q=q0+m2*32+ms*16+lr]
    floatx4 s[2][2] = {};
#pragma unroll
    for (int ku = 0; ku < 2; ++ku) {
      const int krow = ks * 32 + ku * 16 + lr;
      bf16x8 kf0 = ld8(&sK0[krow * TS + qd * 8]);
      bf16x8 kf1 = ld8(&sK1[krow * TS + qd * 8]);
#pragma unroll
      for (int ms = 0; ms < 2; ++ms) {
        s[ms][ku] = mfma16(kf0, qf[ms][0], s[ms][ku]);
        s[ms][ku] = mfma16(kf1, qf[ms][1], s[ms][ku]);
      }
    }

    const bool diag = (kt == qtile);
    uint4 F[2];
#pragma unroll
    for (int ms = 0; ms < 2; ++ms) {
      unsigned W[2][2];             // W[ku][h]: bf16x2 of window-keys ku*16+qd*4+2h+{0,1}
#pragma unroll
      for (int ku = 0; ku < 2; ++ku) {
        float p[4];
#pragma unroll
        for (int i = 0; i < 4; ++i) {
          p[i] = __builtin_amdgcn_exp2f(s[ms][ku][i]);
          if (diag) {
            const int key = kt * 64 + ks * 32 + ku * 16 + qd * 4 + i;
            p[i] = (key <= myq[ms]) ? p[i] : 0.f;
          }
          lsum[ms] += p[i];
        }
        // pack pairs to bf16x2 (truncate; bias cancels in sum(pV)/sum(p))
        W[ku][0] = __builtin_amdgcn_perm(__float_as_uint(p[1]), __float_as_uint(p[0]), 0x07060302);
        W[ku][1] = __builtin_amdgcn_perm(__float_as_uint(p[3]), __float_as_uint(p[2]), 0x07060302);
      }
      // In-register qd-exchange -> A-frag over the wave's 32-key window
      qd_xchg(W[0][0], W[1][0], F[ms].x, F[ms].z);
      qd_xchg(W[0][1], W[1][1], F[ms].y, F[ms].w);
    }
    const bf16x8 pf0 = __builtin_bit_cast(bf16x8, F[0]);
    const bf16x8 pf1 = __builtin_bit_cast(bf16x8, F[1]);

    // O += P V over this wave's 32 keys:
    //   vf = V[key=ks*32+qd*8+e][dim=j*16+lr];  D row=q(qd*4+i), col=dim
#pragma unroll
    for (int j = 0; j < 4; ++j) {
      bf16x8 vf = ld8(&sVk[(j * 16 + lr) * TS + qd * 8]);
      o[0][j] = mfma16(pf0, vf, o[0][j]);
      o[1][j] = mfma16(pf1, vf, o[1][j]);
    }
    __syncthreads();   // drains kt+1 stage (vmcnt0) + protects buf reuse
  }

  // lsum: sum the 4 qd-partials per q within the wave (keys also split by qd)
#pragma unroll
  for (int ms = 0; ms < 2; ++ms) {
    lsum[ms] += __shfl_xor(lsum[ms], 16);
    lsum[ms] += __shfl_xor(lsum[ms], 32);
  }

  // Pairwise ks-reduction through LDS (sKV free after the final barrier).
  // sO: [64 q][68 fp32]  (17408 B, stride 68 breaks qd-group bank pileup)
  // sL: [wave][ms][lr]   (512 B) at offset 17408
  float* sO = (float*)&sKV[0][0][0];
  float* sL = (float*)((char*)&sKV[0][0][0] + 17408);

  if (qd == 0) {
    sL[w * 32 + lr]      = lsum[0];
    sL[w * 32 + 16 + lr] = lsum[1];
  }
  if (ks == 1) {
#pragma unroll
    for (int ms = 0; ms < 2; ++ms)
#pragma unroll
      for (int j = 0; j < 4; ++j)
#pragma unroll
        for (int i = 0; i < 4; ++i)
          sO[(m2 * 32 + ms * 16 + qd * 4 + i) * 68 + j * 16 + lr] = o[ms][j][i];
  }
  __syncthreads();

  if (ks == 0) {
    const int pw = w + 1;           // partner wave (same m2, ks=1)
#pragma unroll
    for (int ms = 0; ms < 2; ++ms) {
      const float lt = lsum[ms] + sL[pw * 32 + ms * 16 + lr];  // qd-replicated
      float linv[4];
#pragma unroll
      for (int i = 0; i < 4; ++i) linv[i] = 1.0f / __shfl(lt, qd * 4 + i);
#pragma unroll
      for (int j = 0; j < 4; ++j)
#pragma unroll
        for (int i = 0; i < 4; ++i) {
          const float ov = o[ms][j][i] +
              sO[(m2 * 32 + ms * 16 + qd * 4 + i) * 68 + j * 16 + lr];
          const size_t row = (size_t)b * TT + q0 + m2 * 32 + ms * 16 + qd * 4 + i;
          att[row * CC + h * HD + j * 16 + lr] = f2bf(ov * linv[i]);
        }
    }
  }
}

// ---------------------------------------------------------------------------
// ws layout (bytes):
//   xb   0        .. 16 MiB   bf16 [8192][1024]
//   waT  16 MiB   .. 22 MiB   bf16 [3072][1024]
//   wpT  22 MiB   .. 24 MiB   bf16 [1024][1024]
//   qk   24 MiB   .. 56 MiB   bf16 [8192][2048]   (Q|K, Q pre-scaled)
//   vT   56 MiB   .. 72 MiB   bf16 [4*1024][2048] (V^T per (b,dim))
//   att  72 MiB   .. 88 MiB   bf16 [8192][1024]
// ---------------------------------------------------------------------------
extern "C" void kernel_launch(void* const* d_in, const int* in_sizes, int n_in,
                              void* d_out, int out_size, void* d_ws, size_t ws_size,
                              hipStream_t stream) {
  const float* x      = (const float*)d_in[0];
  const float* w_attn = (const float*)d_in[1];
  const float* w_proj = (const float*)d_in[2];
  const float* b_proj = (const float*)d_in[3];
  float* out = (float*)d_out;

  char* ws = (char*)d_ws;
  u16* xb  = (u16*)(ws + 0);
  u16* waT = (u16*)(ws + 16777216);
  u16* wpT = (u16*)(ws + 23068672);
  u16* qk  = (u16*)(ws + 25165824);
  u16* vT  = (u16*)(ws + 58720256);
  u16* att = (u16*)(ws + 75497472);

  tobf16_kernel<<<8192, 256, 0, stream>>>((const float4*)x, (ushort4*)xb, 2097152);
  transpose_bf16_kernel<<<dim3(48, 16), 256, 0, stream>>>(w_attn, waT, CC, C3);
  transpose_bf16_kernel<<<dim3(16, 16), 256, 0, stream>>>(w_proj, wpT, CC, CC);

  // qkv = x @ w_attn  (M=8192, N=3072, K=1024) -> qk + vT
  gemm_kernel<1><<<dim3(24, 64), 256, 0, stream>>>(xb, waT, nullptr, nullptr, qk, vT,
                                                   BT, C3, CC);
  // attention: grid (bh, qtile) -> same-bh blocks share an XCD; LPT in y
  attn_kernel<<<dim3(64, 32), 256, 0, stream>>>(qk, vT, att);

  // out = att @ w_proj + b_proj  (M=8192, N=1024, K=1024), fp32 out
  gemm_kernel<2><<<dim3(8, 64), 256, 0, stream>>>(att, wpT, b_proj, out, nullptr, nullptr,
                                                  BT, CC, CC);
}

// Round 6
// 234.348 us; speedup vs baseline: 1.0150x; 1.0150x over previous
//
#include <hip/hip_runtime.h>

// Problem constants
#define BB 4
#define TT 2048
#define CC 1024
#define C3 3072
#define HH 16
#define HD 64
#define BT 8192   // BB*TT

#define TS 32
#define TSZ (64 * TS)   // u16 elements per 64-row sub-tile (4 KB)

typedef __bf16 bf16x8 __attribute__((ext_vector_type(8)));
typedef float floatx4 __attribute__((ext_vector_type(4)));
typedef unsigned uintx2 __attribute__((ext_vector_type(2)));
typedef unsigned short u16;

__device__ __forceinline__ u16 f2bf(float f) {
  union { float f; unsigned u; } a; a.f = f;
  return (u16)((a.u + 0x7fffu + ((a.u >> 16) & 1u)) >> 16);  // RNE
}
__device__ __forceinline__ bf16x8 ld8(const u16* p) { return *(const bf16x8*)p; }
__device__ __forceinline__ floatx4 mfma16(bf16x8 a, bf16x8 b, floatx4 c) {
  return __builtin_amdgcn_mfma_f32_16x16x32_bf16(a, b, c, 0, 0, 0);
}

// Async global->LDS, 16B/lane. LDS dest = wave-uniform base + lane*16 (m104).
__device__ __forceinline__ void gload16(const u16* g, u16* l) {
  __builtin_amdgcn_global_load_lds(
      (const __attribute__((address_space(1))) void*)g,
      (__attribute__((address_space(3))) void*)l, 16, 0, 0);
}

// qd-group redistribution via permlane32/16_swap (verified R3):
//   r0 = [a@0, a@2, b@0, b@2], r1 = [a@1, a@3, b@1, b@3]  (by qd group)
__device__ __forceinline__ void qd_xchg(unsigned a, unsigned b,
                                        unsigned& r0, unsigned& r1) {
  uintx2 t = __builtin_amdgcn_permlane32_swap(a, b, false, false);
  uintx2 r = __builtin_amdgcn_permlane16_swap(t[0], t[1], false, false);
  r0 = r[0]; r1 = r[1];
}

// compiler-fence + hw barrier (no vmcnt drain, unlike __syncthreads)
#define BARR do { asm volatile("" ::: "memory"); \
                  __builtin_amdgcn_s_barrier(); \
                  asm volatile("" ::: "memory"); } while (0)
#define VMW4 asm volatile("s_waitcnt vmcnt(4)" ::: "memory")

// ---------------------------------------------------------------------------
// fp32 -> bf16 elementwise (for x)
// ---------------------------------------------------------------------------
__global__ __launch_bounds__(256) void tobf16_kernel(const float4* __restrict__ src,
                                                     ushort4* __restrict__ dst, int n4) {
  int i = blockIdx.x * 256 + threadIdx.x;
  if (i >= n4) return;
  float4 v = src[i];
  ushort4 o; o.x = f2bf(v.x); o.y = f2bf(v.y); o.z = f2bf(v.z); o.w = f2bf(v.w);
  dst[i] = o;
}

// ---------------------------------------------------------------------------
// fp32 [K][N] -> bf16 [N][K] transpose (LDS-tiled, 64x64 tiles)
// ---------------------------------------------------------------------------
__global__ __launch_bounds__(256) void transpose_bf16_kernel(const float* __restrict__ src,
                                                             u16* __restrict__ dst,
                                                             int K, int N) {
  __shared__ float s[64][65];
  const int t = threadIdx.x;
  const int r = t >> 4;           // 0..15
  const int c = (t & 15) * 4;     // 0..60
  const int k0 = blockIdx.y * 64, n0 = blockIdx.x * 64;
#pragma unroll
  for (int i = 0; i < 4; ++i) {
    float4 v = *(const float4*)&src[(size_t)(k0 + r + i * 16) * N + n0 + c];
    s[r + i * 16][c + 0] = v.x; s[r + i * 16][c + 1] = v.y;
    s[r + i * 16][c + 2] = v.z; s[r + i * 16][c + 3] = v.w;
  }
  __syncthreads();
#pragma unroll
  for (int i = 0; i < 4; ++i) {
    const int nn = r + i * 16;
    ushort4 o;
    o.x = f2bf(s[c + 0][nn]); o.y = f2bf(s[c + 1][nn]);
    o.z = f2bf(s[c + 2][nn]); o.w = f2bf(s[c + 3][nn]);
    *(ushort4*)&dst[(size_t)(n0 + nn) * K + k0 + c] = o;
  }
}

// ---------------------------------------------------------------------------
// R6: 256x256 8-phase GEMM for qkv (M=8192, N=3072, K=1024), 512 thr = 8 waves.
// LDS 128 KiB: lds[parity][A|B][half][128*64 u16], 16B-granular XOR swizzle
//   LDS[row][c] = G[row][c ^ ((row&7)<<3)]  (u16 cols; inverse-swizzled global
//   SOURCE on gload_lds + swizzled ds_read addr -> 2-way banks = free).
// Wave w: wm2=w>>2 (A 64-row slice in each A-half), wn4=w&3 (B 32-row slice).
// Phase = quadrant (MQ,NQ) of K-tile: all waves read A-half MQ + B-half NQ ->
//   4x2x2 = 16 MFMA/phase; quadrant order (0,0),(1,0),(0,1),(1,1).
// Slot-ring stages (each targets a slot freed at the PREVIOUS barrier):
//   ph0: A1,B1(To)  ph2: B0(Te+2)  ph3: A0(Te+2)+vmcnt(4)  ph4: A1(Te+2)
//   ph5: B1(Te+2)   ph6: B0(To+2)  ph7: A0(To+2)+vmcnt(4)
// vmcnt(4) leaves exactly the 2 newest half-tiles in flight -> everything a
// subsequent phase reads has landed (checked phase-by-phase).  Never drains.
// Epilogue: Q/K row-major bounce (Q pre-scaled 0.125*log2e), V transpose
// bounce -> vT, reusing the 128 KiB LDS after the final barrier.
// ---------------------------------------------------------------------------
__global__ __launch_bounds__(512, 2) void gemm256_kernel(
    const u16* __restrict__ A, const u16* __restrict__ B,
    u16* __restrict__ qk, u16* __restrict__ vT, int K) {
  __shared__ u16 lds[2][2][2][8192];   // 128 KiB

  const int t = threadIdx.x;           // 0..511
  const int lane = t & 63, lr = lane & 15, qd = lane >> 4;
  const int w = t >> 6, wm2 = w >> 2, wn4 = w & 3;
  const int m0 = blockIdx.y * 256, n0 = blockIdx.x * 256;

  // staging: thread t covers 16B at row t>>3, inverse-swizzled col
  const int srow = t >> 3;
  const int scol = ((t & 7) ^ (srow & 7)) * 8;   // u16
  const u16* Asrc = A + (size_t)(m0 + srow) * K + scol;
  const u16* Bsrc = B + (size_t)(n0 + srow) * K + scol;
  const int wvb = (t & ~63) * 8;       // wave-uniform dest base (u16)

  const int NT = K >> 6;               // 64-wide K-tiles (16)
  floatx4 acc[8][4] = {};

  // ds_read swizzle constants (row&7 == lr&7 for all frag rows)
  const int lr64 = lr * 64;
  const int csw0 = (qd * 8) ^ ((lr & 7) * 8);
  const int csw1 = (32 + qd * 8) ^ ((lr & 7) * 8);

  // stage one half-tile (2 x gload16: rows 0-63, 64-127 of the half)
#define STG(PR, MT, HF, TK) do { if ((TK) < NT) { \
    const u16* g_ = ((MT) ? Bsrc : Asrc) + (size_t)((HF) * 128) * K + (TK) * 64; \
    u16* l_ = &lds[PR][MT][HF][wvb]; \
    gload16(g_, l_); \
    gload16(g_ + (size_t)64 * K, l_ + 4096); } } while (0)

#define PHASE(PR, MQ, NQ) do { \
    const u16* As_ = &lds[PR][0][MQ][0]; \
    const u16* Bs_ = &lds[PR][1][NQ][0]; \
    bf16x8 af_[4][2], bf_[2][2]; \
    _Pragma("unroll") \
    for (int mi = 0; mi < 4; ++mi) { \
      const int rb = (wm2 * 64 + mi * 16) * 64 + lr64; \
      af_[mi][0] = ld8(&As_[rb + csw0]); af_[mi][1] = ld8(&As_[rb + csw1]); } \
    _Pragma("unroll") \
    for (int ni = 0; ni < 2; ++ni) { \
      const int rb = (wn4 * 32 + ni * 16) * 64 + lr64; \
      bf_[ni][0] = ld8(&Bs_[rb + csw0]); bf_[ni][1] = ld8(&Bs_[rb + csw1]); } \
    __builtin_amdgcn_s_setprio(1); \
    _Pragma("unroll") \
    for (int mi = 0; mi < 4; ++mi) \
      _Pragma("unroll") \
      for (int ni = 0; ni < 2; ++ni) { \
        acc[(MQ)*4+mi][(NQ)*2+ni] = mfma16(af_[mi][0], bf_[ni][0], acc[(MQ)*4+mi][(NQ)*2+ni]); \
        acc[(MQ)*4+mi][(NQ)*2+ni] = mfma16(af_[mi][1], bf_[ni][1], acc[(MQ)*4+mi][(NQ)*2+ni]); } \
    __builtin_amdgcn_s_setprio(0); \
  } while (0)

  // prologue: T0 {A0,B0,A1,B1}, T1 {B0,A0}; vmcnt(4) leaves T1's 4 in flight
  STG(0, 0, 0, 0); STG(0, 1, 0, 0); STG(0, 0, 1, 0); STG(0, 1, 1, 0);
  STG(1, 1, 0, 1); STG(1, 0, 0, 1);
  VMW4; BARR;

  for (int it = 0; it < 8; ++it) {
    const int To = 2 * it + 1, Tn = 2 * it + 2, Tm = 2 * it + 3;
    STG(1, 0, 1, To); STG(1, 1, 1, To); PHASE(0, 0, 0);       BARR;  // ph0
    PHASE(0, 1, 0);                                            BARR;  // ph1
    STG(0, 1, 0, Tn); PHASE(0, 0, 1);                          BARR;  // ph2
    STG(0, 0, 0, Tn); PHASE(0, 1, 1);                    VMW4; BARR;  // ph3
    STG(0, 0, 1, Tn); PHASE(1, 0, 0);                          BARR;  // ph4
    STG(0, 1, 1, Tn); PHASE(1, 1, 0);                          BARR;  // ph5
    STG(1, 1, 0, Tm); PHASE(1, 0, 1);                          BARR;  // ph6
    STG(1, 0, 0, Tm); PHASE(1, 1, 1);                    VMW4; BARR;  // ph7
  }
#undef STG
#undef PHASE

  // ---- epilogue: all loads landed, final barrier passed; reuse LDS ----
  const bool isV = (n0 >= 2 * CC);     // block-uniform
  if (!isV) {
    const float qs = (n0 < CC) ? 0.18033688011f : 1.0f;
    u16* Tw = ((u16*)&lds[0][0][0][0]) + w * (32 * 40);  // [32 rows][40] 16B-aligned
#pragma unroll
    for (int mq = 0; mq < 2; ++mq)
#pragma unroll
      for (int mi2 = 0; mi2 < 2; ++mi2)
#pragma unroll
        for (int nq = 0; nq < 2; ++nq) {
#pragma unroll
          for (int mh = 0; mh < 2; ++mh)
#pragma unroll
            for (int ni = 0; ni < 2; ++ni)
#pragma unroll
              for (int i = 0; i < 4; ++i)
                Tw[(mh * 16 + qd * 4 + i) * 40 + ni * 16 + lr] =
                    f2bf(acc[mq * 4 + mi2 * 2 + mh][nq * 2 + ni][i] * qs);
          const int R0 = m0 + mq * 128 + wm2 * 64 + mi2 * 32;
          const int C0 = n0 + nq * 128 + wn4 * 32;
#pragma unroll
          for (int s = 0; s < 2; ++s) {
            const int rl = s * 16 + (lane >> 2);
            const int c0 = (lane & 3) * 8;
            *(bf16x8*)&qk[(size_t)(R0 + rl) * (2 * CC) + C0 + c0] =
                ld8(&Tw[rl * 40 + c0]);
          }
        }
  } else {
    u16* Tv = ((u16*)&lds[0][0][0][0]) + w * (32 * 72);  // [32 dims][72]
    const int bI = m0 >> 11;
#pragma unroll
    for (int mq = 0; mq < 2; ++mq) {
      const int tbase = (m0 & (TT - 1)) + mq * 128 + wm2 * 64;
#pragma unroll
      for (int nq = 0; nq < 2; ++nq) {
        const int dim0 = (n0 - 2 * CC) + nq * 128 + wn4 * 32;
#pragma unroll
        for (int ni = 0; ni < 2; ++ni)
#pragma unroll
          for (int mi = 0; mi < 4; ++mi)
#pragma unroll
            for (int i = 0; i < 4; ++i)
              Tv[(ni * 16 + lr) * 72 + mi * 16 + qd * 4 + i] =
                  f2bf(acc[mq * 4 + mi][nq * 2 + ni][i]);
#pragma unroll
        for (int s = 0; s < 4; ++s) {
          const int dl = s * 8 + (lane >> 3);
          const int t0 = (lane & 7) * 8;
          *(bf16x8*)&vT[((size_t)(bI << 10) + dim0 + dl) * TT + tbase + t0] =
              ld8(&Tv[dl * 72 + t0]);
        }
      }
    }
  }
}

// ---------------------------------------------------------------------------
// GEMM: C[M,N] = A[M,K] @ B^T[N,K], 128x128 tile, BK=32, 256 thr = 4 waves.
// global_load_lds staging; one barrier per K-iter (R4, verified).
// MODE 2: fp32 out + bias, direct stores (used for the proj GEMM, where a
// 256^2 grid would be only 128 blocks -> half the CUs idle).
// ---------------------------------------------------------------------------
template<int MODE>
__global__ __launch_bounds__(256) void gemm_kernel(
    const u16* __restrict__ A, const u16* __restrict__ B,
    const float* __restrict__ bias, float* __restrict__ outf,
    int M, int N, int K) {
  __shared__ u16 smem[2][2][2 * TSZ];   // [buf][A|B][128 rows x TS] = 32 KB

  const int t = threadIdx.x;
  const int w = t >> 6, lane = t & 63, lr = lane & 15, qd = lane >> 4;
  const int wm = w >> 1, wn = w & 1;
  const int m0 = blockIdx.y * 128, n0 = blockIdx.x * 128;

  const int sr = t >> 2;
  const int sc = (t & 3) * 8;
  const int wb = (t & ~63) * 8;
  const u16* Ag = A + (size_t)(m0 + sr) * K + sc;
  const u16* Bg = B + (size_t)(n0 + sr) * K + sc;

  floatx4 acc[4][4] = {};

  {  // prologue: stage tile 0 into buf 0
    u16* sA = &smem[0][0][0];
    u16* sB = &smem[0][1][0];
    gload16(Ag,                  &sA[wb]);
    gload16(Ag + (size_t)64 * K, &sA[TSZ + wb]);
    gload16(Bg,                  &sB[wb]);
    gload16(Bg + (size_t)64 * K, &sB[TSZ + wb]);
  }
  __syncthreads();

  for (int k0 = 0; k0 < K; k0 += 32) {
    const int p = (k0 >> 5) & 1;
    if (k0 + 32 < K) {               // stage next tile into the OTHER buffer
      u16* sA = &smem[p ^ 1][0][0];
      u16* sB = &smem[p ^ 1][1][0];
      gload16(Ag + k0 + 32,                  &sA[wb]);
      gload16(Ag + (size_t)64 * K + k0 + 32, &sA[TSZ + wb]);
      gload16(Bg + k0 + 32,                  &sB[wb]);
      gload16(Bg + (size_t)64 * K + k0 + 32, &sB[TSZ + wb]);
    }
    const u16* sA = &smem[p][0][0];
    const u16* sB = &smem[p][1][0];

    bf16x8 af[4], bf[4];
#pragma unroll
    for (int mj = 0; mj < 4; ++mj) af[mj] = ld8(&sA[(wm * 64 + mj * 16 + lr) * TS + qd * 8]);
#pragma unroll
    for (int nj = 0; nj < 4; ++nj) bf[nj] = ld8(&sB[(wn * 64 + nj * 16 + lr) * TS + qd * 8]);
#pragma unroll
    for (int mj = 0; mj < 4; ++mj)
#pragma unroll
      for (int nj = 0; nj < 4; ++nj)
        acc[mj][nj] = mfma16(af[mj], bf[nj], acc[mj][nj]);
    __syncthreads();   // drains next-tile stage (vmcnt0) + protects buf reuse
  }

  // Epilogue. D layout: col(N)=lane&15, row(M)=(lane>>4)*4+i  [m89/m91]
  const int rowg0 = m0 + wm * 64;
  const int colg0 = n0 + wn * 64;
#pragma unroll
  for (int nj = 0; nj < 4; ++nj) {
    const int col = colg0 + nj * 16 + lr;
    const float bv = bias[col];
#pragma unroll
    for (int mj = 0; mj < 4; ++mj)
#pragma unroll
      for (int i = 0; i < 4; ++i)
        outf[(size_t)(rowg0 + mj * 16 + qd * 4 + i) * N + col] = acc[mj][nj][i] + bv;
  }
}

// ---------------------------------------------------------------------------
// Causal flash attention (R4 version restored; R5 key-split was neutral).
// Wave = 16 q, block = 64 q.  K/V staging via global_load_lds, one barrier
// per kt.  In-register P via permlane (R3).  Q pre-scaled by 0.125*log2e.
// ---------------------------------------------------------------------------
__global__ __launch_bounds__(256, 5) void attn_kernel(const u16* __restrict__ qk,
                                                      const u16* __restrict__ vT,
                                                      u16* __restrict__ att) {
  __shared__ u16 sKV[2][4][TSZ];      // [buf][K0,K1,V0,V1] = 32768 B

  const int t = threadIdx.x;
  const int w = t >> 6, lane = t & 63, lr = lane & 15, qd = lane >> 4;
  const int qtile = 31 - blockIdx.y;  // LPT: longest first
  const int bh = blockIdx.x;          // x fastest -> XCD = bh % 8 for all qtiles
  const int b = bh >> 4, h = bh & 15;
  const int q0 = qtile * 64;
  const u16* qbase = qk + (size_t)b * TT * (2 * CC);

  const u16* qp = qbase + (size_t)(q0 + w * 16 + lr) * (2 * CC) + h * HD;
  const bf16x8 qf0 = ld8(qp + qd * 8);
  const bf16x8 qf1 = ld8(qp + 32 + qd * 8);

  const int sr = t >> 2, sc = (t & 3) * 8;
  const int wb = (t & ~63) * 8;   // wave-uniform u16 base within a sub-tile
  const u16* Kg = qbase + (size_t)sr * (2 * CC) + CC + h * HD + sc;
  const u16* Vg = vT + ((size_t)bh * HD + sr) * TT + sc;

  float lsum = 0.f;                 // per-lane partial: q = lr
  floatx4 o[4] = {};
  const int myq = q0 + w * 16 + lr;

  {  // prologue: stage tile 0 into buf 0
    u16* b0 = &sKV[0][0][0];
    gload16(Kg,      &b0[wb]);
    gload16(Kg + 32, &b0[TSZ + wb]);
    gload16(Vg,      &b0[2 * TSZ + wb]);
    gload16(Vg + 32, &b0[3 * TSZ + wb]);
  }
  __syncthreads();

  for (int kt = 0; kt <= qtile; ++kt) {
    if (kt < qtile) {               // stage kt+1 into the OTHER buffer
      const int kn = (kt + 1) * 64;
      u16* bn = &sKV[(kt + 1) & 1][0][0];
      gload16(Kg + (size_t)kn * (2 * CC),      &bn[wb]);
      gload16(Kg + (size_t)kn * (2 * CC) + 32, &bn[TSZ + wb]);
      gload16(Vg + kn,                         &bn[2 * TSZ + wb]);
      gload16(Vg + kn + 32,                    &bn[3 * TSZ + wb]);
    }

    const u16* sK0 = &sKV[kt & 1][0][0];
    const u16* sK1 = &sKV[kt & 1][1][0];
    const u16* sV0 = &sKV[kt & 1][2][0];
    const u16* sV1 = &sKV[kt & 1][3][0];

    // S^T = K Q^T: frag j -> element (key = kt*64+j*16+qd*4+i, q = lr)
    floatx4 s[4] = {};
#pragma unroll
    for (int j = 0; j < 4; ++j) {
      bf16x8 kf0 = ld8(&sK0[(j * 16 + lr) * TS + qd * 8]);
      bf16x8 kf1 = ld8(&sK1[(j * 16 + lr) * TS + qd * 8]);
      s[j] = mfma16(kf0, qf0, s[j]);
      s[j] = mfma16(kf1, qf1, s[j]);
    }

    const bool diag = (kt == qtile);
    unsigned W[4][2];               // W[j][h]: bf16x2 of keys j*16+qd*4+2h+{0,1}
#pragma unroll
    for (int j = 0; j < 4; ++j) {
      float p[4];
#pragma unroll
      for (int i = 0; i < 4; ++i) {
        p[i] = __builtin_amdgcn_exp2f(s[j][i]);
        if (diag) {
          const int key = kt * 64 + j * 16 + qd * 4 + i;
          p[i] = (key <= myq) ? p[i] : 0.f;
        }
        lsum += p[i];
      }
      W[j][0] = __builtin_amdgcn_perm(__float_as_uint(p[1]), __float_as_uint(p[0]), 0x07060302);
      W[j][1] = __builtin_amdgcn_perm(__float_as_uint(p[3]), __float_as_uint(p[2]), 0x07060302);
    }

    uint4 F0, F1;
    qd_xchg(W[0][0], W[1][0], F0.x, F0.z);
    qd_xchg(W[0][1], W[1][1], F0.y, F0.w);
    qd_xchg(W[2][0], W[3][0], F1.x, F1.z);
    qd_xchg(W[2][1], W[3][1], F1.y, F1.w);
    const bf16x8 pf0 = __builtin_bit_cast(bf16x8, F0);
    const bf16x8 pf1 = __builtin_bit_cast(bf16x8, F1);

    // O += P V: D row = q (qd*4+i), col = dim (j*16+lr)
#pragma unroll
    for (int j = 0; j < 4; ++j) {
      bf16x8 vf0 = ld8(&sV0[(j * 16 + lr) * TS + qd * 8]);
      bf16x8 vf1 = ld8(&sV1[(j * 16 + lr) * TS + qd * 8]);
      o[j] = mfma16(pf0, vf0, o[j]);
      o[j] = mfma16(pf1, vf1, o[j]);
    }
    __syncthreads();   // drains kt+1 stage (vmcnt0) + protects buf reuse
  }

  lsum += __shfl_xor(lsum, 16);
  lsum += __shfl_xor(lsum, 32);
  float linv[4];
#pragma unroll
  for (int i = 0; i < 4; ++i) linv[i] = 1.0f / __shfl(lsum, qd * 4 + i);

#pragma unroll
  for (int j = 0; j < 4; ++j)
#pragma unroll
    for (int i = 0; i < 4; ++i) {
      const size_t row = (size_t)b * TT + q0 + w * 16 + qd * 4 + i;
      att[row * CC + h * HD + j * 16 + lr] = f2bf(o[j][i] * linv[i]);
    }
}

// ---------------------------------------------------------------------------
// ws layout (bytes):
//   xb   0        .. 16 MiB   bf16 [8192][1024]
//   waT  16 MiB   .. 22 MiB   bf16 [3072][1024]
//   wpT  22 MiB   .. 24 MiB   bf16 [1024][1024]
//   qk   24 MiB   .. 56 MiB   bf16 [8192][2048]   (Q|K, Q pre-scaled)
//   vT   56 MiB   .. 72 MiB   bf16 [4*1024][2048] (V^T per (b,dim))
//   att  72 MiB   .. 88 MiB   bf16 [8192][1024]
// ---------------------------------------------------------------------------
extern "C" void kernel_launch(void* const* d_in, const int* in_sizes, int n_in,
                              void* d_out, int out_size, void* d_ws, size_t ws_size,
                              hipStream_t stream) {
  const float* x      = (const float*)d_in[0];
  const float* w_attn = (const float*)d_in[1];
  const float* w_proj = (const float*)d_in[2];
  const float* b_proj = (const float*)d_in[3];
  float* out = (float*)d_out;

  char* ws = (char*)d_ws;
  u16* xb  = (u16*)(ws + 0);
  u16* waT = (u16*)(ws + 16777216);
  u16* wpT = (u16*)(ws + 23068672);
  u16* qk  = (u16*)(ws + 25165824);
  u16* vT  = (u16*)(ws + 58720256);
  u16* att = (u16*)(ws + 75497472);

  tobf16_kernel<<<8192, 256, 0, stream>>>((const float4*)x, (ushort4*)xb, 2097152);
  transpose_bf16_kernel<<<dim3(48, 16), 256, 0, stream>>>(w_attn, waT, CC, C3);
  transpose_bf16_kernel<<<dim3(16, 16), 256, 0, stream>>>(w_proj, wpT, CC, CC);

  // qkv = x @ w_attn  (M=8192, N=3072, K=1024) -> qk + vT   [256^2 8-phase]
  gemm256_kernel<<<dim3(12, 32), 512, 0, stream>>>(xb, waT, qk, vT, CC);

  // attention: grid (bh, qtile) -> same-bh blocks share an XCD; LPT in y
  attn_kernel<<<dim3(64, 32), 256, 0, stream>>>(qk, vT, att);

  // out = att @ w_proj + b_proj  (M=8192, N=1024, K=1024), fp32 out
  gemm_kernel<2><<<dim3(8, 64), 256, 0, stream>>>(att, wpT, b_proj, out,
                                                  BT, CC, CC);
}

// Round 7
// 232.557 us; speedup vs baseline: 1.0229x; 1.0077x over previous
//
#include <hip/hip_runtime.h>

// Problem constants
#define BB 4
#define TT 2048
#define CC 1024
#define C3 3072
#define HH 16
#define HD 64
#define BT 8192   // BB*TT

#define TS 32
#define TSZ (64 * TS)   // u16 elements per 64-row sub-tile (4 KB)

typedef __bf16 bf16x8 __attribute__((ext_vector_type(8)));
typedef float floatx4 __attribute__((ext_vector_type(4)));
typedef unsigned uintx2 __attribute__((ext_vector_type(2)));
typedef unsigned short u16;

__device__ __forceinline__ u16 f2bf(float f) {
  union { float f; unsigned u; } a; a.f = f;
  return (u16)((a.u + 0x7fffu + ((a.u >> 16) & 1u)) >> 16);  // RNE
}
__device__ __forceinline__ bf16x8 ld8(const u16* p) { return *(const bf16x8*)p; }
__device__ __forceinline__ floatx4 mfma16(bf16x8 a, bf16x8 b, floatx4 c) {
  return __builtin_amdgcn_mfma_f32_16x16x32_bf16(a, b, c, 0, 0, 0);
}

// Async global->LDS, 16B/lane. LDS dest = wave-uniform base + lane*16 (m104).
__device__ __forceinline__ void gload16(const u16* g, u16* l) {
  __builtin_amdgcn_global_load_lds(
      (const __attribute__((address_space(1))) void*)g,
      (__attribute__((address_space(3))) void*)l, 16, 0, 0);
}

// qd-group redistribution via permlane32/16_swap (verified R3):
//   r0 = [a@0, a@2, b@0, b@2], r1 = [a@1, a@3, b@1, b@3]  (by qd group)
__device__ __forceinline__ void qd_xchg(unsigned a, unsigned b,
                                        unsigned& r0, unsigned& r1) {
  uintx2 t = __builtin_amdgcn_permlane32_swap(a, b, false, false);
  uintx2 r = __builtin_amdgcn_permlane16_swap(t[0], t[1], false, false);
  r0 = r[0]; r1 = r[1];
}

// compiler-fence + hw barrier (no vmcnt drain, unlike __syncthreads)
#define BARR do { asm volatile("" ::: "memory"); \
                  __builtin_amdgcn_s_barrier(); \
                  asm volatile("" ::: "memory"); } while (0)
#define VMW4 asm volatile("s_waitcnt vmcnt(4)" ::: "memory")
#define VMW0 asm volatile("s_waitcnt vmcnt(0)" ::: "memory")

// ---------------------------------------------------------------------------
// fp32 -> bf16 elementwise (for x)
// ---------------------------------------------------------------------------
__global__ __launch_bounds__(256) void tobf16_kernel(const float4* __restrict__ src,
                                                     ushort4* __restrict__ dst, int n4) {
  int i = blockIdx.x * 256 + threadIdx.x;
  if (i >= n4) return;
  float4 v = src[i];
  ushort4 o; o.x = f2bf(v.x); o.y = f2bf(v.y); o.z = f2bf(v.z); o.w = f2bf(v.w);
  dst[i] = o;
}

// ---------------------------------------------------------------------------
// fp32 [K][N] -> bf16 [N][K] transpose (LDS-tiled, 64x64 tiles)
// ---------------------------------------------------------------------------
__global__ __launch_bounds__(256) void transpose_bf16_kernel(const float* __restrict__ src,
                                                             u16* __restrict__ dst,
                                                             int K, int N) {
  __shared__ float s[64][65];
  const int t = threadIdx.x;
  const int r = t >> 4;           // 0..15
  const int c = (t & 15) * 4;     // 0..60
  const int k0 = blockIdx.y * 64, n0 = blockIdx.x * 64;
#pragma unroll
  for (int i = 0; i < 4; ++i) {
    float4 v = *(const float4*)&src[(size_t)(k0 + r + i * 16) * N + n0 + c];
    s[r + i * 16][c + 0] = v.x; s[r + i * 16][c + 1] = v.y;
    s[r + i * 16][c + 2] = v.z; s[r + i * 16][c + 3] = v.w;
  }
  __syncthreads();
#pragma unroll
  for (int i = 0; i < 4; ++i) {
    const int nn = r + i * 16;
    ushort4 o;
    o.x = f2bf(s[c + 0][nn]); o.y = f2bf(s[c + 1][nn]);
    o.z = f2bf(s[c + 2][nn]); o.w = f2bf(s[c + 3][nn]);
    *(ushort4*)&dst[(size_t)(n0 + nn) * K + k0 + c] = o;
  }
}

// ---------------------------------------------------------------------------
// R7: 256x128 4-phase GEMM, 512 thr = 8 waves (4M x 2N), 64x64 out per wave.
// Fixes R6's two port defects: grid tail (qkv 768 = 3x256 exact rounds,
// proj 256 = 1 round) and LDS-read ratio (16 ds_read_b128 per 32 MFMA = 0.5,
// A-frags reused across the 2 phases of a K-tile; R6 was 0.75).
// LDS 96 KiB: lds[parity][ A 256x64 | B 128x64 ] u16, 16B-granular XOR
// swizzle LDS[row][c] = G[row][c ^ ((row&7)*8)] (inverse-swizzled global src
// on gload_lds + swizzled ds_read -> conflict-free).
// Schedule (2 K-tiles per iter, 4 phases, 2 barriers/K-tile):
//   ph0: stage B(2i+1)->buf1; read buf0 A + B01; 16 MFMA;            BARR
//   ph1: stage A(2i+2)->buf0; read buf0 B23;     16 MFMA; vmcnt(4);  BARR
//   ph2: stage B(2i+2)->buf0; read buf1 A + B01; 16 MFMA;            BARR
//   ph3: stage A(2i+3)->buf1; read buf1 B23;     16 MFMA; vmcnt(4);  BARR
// Ledger (verified): each slot staged in the phase after its last reader's
// barrier; vmcnt(4) leaves exactly the newest A-stage (4 loads) in flight and
// drains everything the next two phases read.  Last iter: skipped stages
// break the count -> vmcnt(0).
// MODE 1: qkv epilogue (Q pre-scaled 0.125*log2e; Q/K row bounce; V
//         transpose bounce -> vT).  MODE 2: fp32 out + bias, direct.
// ---------------------------------------------------------------------------
template<int MODE>
__global__ __launch_bounds__(512, 2) void gemm256_kernel(
    const u16* __restrict__ A, const u16* __restrict__ B,
    const float* __restrict__ bias, float* __restrict__ outf,
    u16* __restrict__ qk, u16* __restrict__ vT, int N, int K) {
  __shared__ u16 lds[2][24576];   // [parity][A:0..16383 | B:16384..24575] 96 KiB

  const int t = threadIdx.x;      // 0..511
  const int lane = t & 63, lr = lane & 15, qd = lane >> 4;
  const int w = t >> 6, wm = w >> 1, wn = w & 1;
  const int m0 = blockIdx.y * 256, n0 = blockIdx.x * 128;

  // staging: thread t covers 16B at row t>>3 (0..63 per gload unit),
  // inverse-swizzled col; wave w writes LDS bytes [w KiB, (w+1) KiB).
  const int srow = t >> 3;
  const int scol = ((t & 7) ^ (srow & 7)) * 8;   // u16
  const u16* Asrc = A + (size_t)(m0 + srow) * K + scol;
  const u16* Bsrc = B + (size_t)(n0 + srow) * K + scol;
  const int wvb = (t & ~63) * 8;                 // wave-uniform u16 base

  const int NT = K >> 6;          // 64-wide K-tiles (16)
  floatx4 acc[4][4] = {};

  const int abase = (wm * 64 + lr) * 64;
  const int bbase = (wn * 64 + lr) * 64;
  const int csw0 = (qd * 8) ^ ((lr & 7) * 8);
  const int csw1 = (32 + qd * 8) ^ ((lr & 7) * 8);

#define STG_A(PR, QA, TK) do { if ((TK) < NT) \
    gload16(Asrc + (size_t)((QA) * 64) * K + (TK) * 64, \
            &lds[PR][(QA) * 4096 + wvb]); } while (0)
#define STG_B(PR, HB, TK) do { if ((TK) < NT) \
    gload16(Bsrc + (size_t)((HB) * 64) * K + (TK) * 64, \
            &lds[PR][16384 + (HB) * 4096 + wvb]); } while (0)

  bf16x8 af[4][2], bf[2][2];
#define READ_A(PR) do { _Pragma("unroll") for (int mi = 0; mi < 4; ++mi) { \
    const u16* p_ = &lds[PR][mi * 1024 + abase]; \
    af[mi][0] = ld8(p_ + csw0); af[mi][1] = ld8(p_ + csw1); } } while (0)
#define READ_B(PR, NJ0) do { _Pragma("unroll") for (int nj = 0; nj < 2; ++nj) { \
    const u16* p_ = &lds[PR][16384 + ((NJ0) + nj) * 1024 + bbase]; \
    bf[nj][0] = ld8(p_ + csw0); bf[nj][1] = ld8(p_ + csw1); } } while (0)
#define MFMA16(NJ0) do { __builtin_amdgcn_s_setprio(1); _Pragma("unroll") \
    for (int mi = 0; mi < 4; ++mi) _Pragma("unroll") for (int nj = 0; nj < 2; ++nj) { \
      acc[mi][(NJ0) + nj] = mfma16(af[mi][0], bf[nj][0], acc[mi][(NJ0) + nj]); \
      acc[mi][(NJ0) + nj] = mfma16(af[mi][1], bf[nj][1], acc[mi][(NJ0) + nj]); } \
    __builtin_amdgcn_s_setprio(0); } while (0)

  // prologue: A(0),B(0) -> buf0; A(1) -> buf1.  vmcnt(4) leaves A(1) in flight.
  STG_A(0, 0, 0); STG_A(0, 1, 0); STG_A(0, 2, 0); STG_A(0, 3, 0);
  STG_B(0, 0, 0); STG_B(0, 1, 0);
  STG_A(1, 0, 1); STG_A(1, 1, 1); STG_A(1, 2, 1); STG_A(1, 3, 1);
  VMW4; BARR;

  const int NITER = NT >> 1;
  for (int it = 0; it < NITER; ++it) {
    const int T1 = 2 * it + 1, T2 = 2 * it + 2, T3 = 2 * it + 3;
    const bool last = (it == NITER - 1);
    // ph0: even tile (buf0) first half
    STG_B(1, 0, T1); STG_B(1, 1, T1);
    READ_A(0); READ_B(0, 0); MFMA16(0);
    BARR;
    // ph1: even tile second half (af reused)
    STG_A(0, 0, T2); STG_A(0, 1, T2); STG_A(0, 2, T2); STG_A(0, 3, T2);
    READ_B(0, 2); MFMA16(2);
    if (last) { VMW0; } else { VMW4; }
    BARR;
    // ph2: odd tile (buf1) first half
    STG_B(0, 0, T2); STG_B(0, 1, T2);
    READ_A(1); READ_B(1, 0); MFMA16(0);
    BARR;
    // ph3: odd tile second half
    STG_A(1, 0, T3); STG_A(1, 1, T3); STG_A(1, 2, T3); STG_A(1, 3, T3);
    READ_B(1, 2); MFMA16(2);
    if (last) { VMW0; } else { VMW4; }
    BARR;
  }
#undef STG_A
#undef STG_B
#undef READ_A
#undef READ_B
#undef MFMA16

  // ---- epilogue: all DMAs landed (vmcnt0 on last iter) + final barrier ----
  // D layout: col(N)=lane&15, row(M)=(lane>>4)*4+i  [m89/m91]
  u16* flat = &lds[0][0];
  if constexpr (MODE == 2) {
    const int rowg0 = m0 + wm * 64;
    const int colg0 = n0 + wn * 64;
#pragma unroll
    for (int nj = 0; nj < 4; ++nj) {
      const int col = colg0 + nj * 16 + lr;
      const float bv = bias[col];
#pragma unroll
      for (int mi = 0; mi < 4; ++mi)
#pragma unroll
        for (int i = 0; i < 4; ++i)
          outf[(size_t)(rowg0 + mi * 16 + qd * 4 + i) * N + col] = acc[mi][nj][i] + bv;
    }
  } else {
    const bool isV = (n0 >= 2 * CC);   // block-uniform
    if (!isV) {
      const float qs = (n0 < CC) ? 0.18033688011f : 1.0f;
      u16* Tw = flat + w * (32 * 72);  // per-wave [32 rows][72]
      const int C0 = n0 + wn * 64;
#pragma unroll
      for (int mi2 = 0; mi2 < 2; ++mi2) {
#pragma unroll
        for (int mh = 0; mh < 2; ++mh)
#pragma unroll
          for (int nj = 0; nj < 4; ++nj)
#pragma unroll
            for (int i = 0; i < 4; ++i)
              Tw[(mh * 16 + qd * 4 + i) * 72 + nj * 16 + lr] =
                  f2bf(acc[mi2 * 2 + mh][nj][i] * qs);
        const int R0 = m0 + wm * 64 + mi2 * 32;
#pragma unroll
        for (int s = 0; s < 4; ++s) {
          const int rl = s * 8 + (lane >> 3);
          const int c0 = (lane & 7) * 8;
          *(bf16x8*)&qk[(size_t)(R0 + rl) * (2 * CC) + C0 + c0] =
              ld8(&Tw[rl * 72 + c0]);
        }
      }
    } else {
      u16* Tv = flat + w * (64 * 72);  // per-wave [64 dims][72]
      const int bI = m0 >> 11;
      const int tbase = (m0 & (TT - 1)) + wm * 64;
      const int dim0 = (n0 - 2 * CC) + wn * 64;
#pragma unroll
      for (int nj = 0; nj < 4; ++nj)
#pragma unroll
        for (int mi = 0; mi < 4; ++mi)
#pragma unroll
          for (int i = 0; i < 4; ++i)
            Tv[(nj * 16 + lr) * 72 + mi * 16 + qd * 4 + i] =
                f2bf(acc[mi][nj][i]);
#pragma unroll
      for (int s = 0; s < 8; ++s) {
        const int dl = s * 8 + (lane >> 3);
        const int t0 = (lane & 7) * 8;
        *(bf16x8*)&vT[((size_t)(bI << 10) + dim0 + dl) * TT + tbase + t0] =
            ld8(&Tv[dl * 72 + t0]);
      }
    }
  }
}

// ---------------------------------------------------------------------------
// Causal flash attention (R4 version).  Wave = 16 q, block = 64 q.  K/V
// staging via global_load_lds, one barrier per kt.  In-register P via
// permlane (R3).  Q pre-scaled by 0.125*log2e.
// ---------------------------------------------------------------------------
__global__ __launch_bounds__(256, 5) void attn_kernel(const u16* __restrict__ qk,
                                                      const u16* __restrict__ vT,
                                                      u16* __restrict__ att) {
  __shared__ u16 sKV[2][4][TSZ];      // [buf][K0,K1,V0,V1] = 32768 B

  const int t = threadIdx.x;
  const int w = t >> 6, lane = t & 63, lr = lane & 15, qd = lane >> 4;
  const int qtile = 31 - blockIdx.y;  // LPT: longest first
  const int bh = blockIdx.x;          // x fastest -> XCD = bh % 8 for all qtiles
  const int b = bh >> 4, h = bh & 15;
  const int q0 = qtile * 64;
  const u16* qbase = qk + (size_t)b * TT * (2 * CC);

  const u16* qp = qbase + (size_t)(q0 + w * 16 + lr) * (2 * CC) + h * HD;
  const bf16x8 qf0 = ld8(qp + qd * 8);
  const bf16x8 qf1 = ld8(qp + 32 + qd * 8);

  const int sr = t >> 2, sc = (t & 3) * 8;
  const int wb = (t & ~63) * 8;   // wave-uniform u16 base within a sub-tile
  const u16* Kg = qbase + (size_t)sr * (2 * CC) + CC + h * HD + sc;
  const u16* Vg = vT + ((size_t)bh * HD + sr) * TT + sc;

  float lsum = 0.f;                 // per-lane partial: q = lr
  floatx4 o[4] = {};
  const int myq = q0 + w * 16 + lr;

  {  // prologue: stage tile 0 into buf 0
    u16* b0 = &sKV[0][0][0];
    gload16(Kg,      &b0[wb]);
    gload16(Kg + 32, &b0[TSZ + wb]);
    gload16(Vg,      &b0[2 * TSZ + wb]);
    gload16(Vg + 32, &b0[3 * TSZ + wb]);
  }
  __syncthreads();

  for (int kt = 0; kt <= qtile; ++kt) {
    if (kt < qtile) {               // stage kt+1 into the OTHER buffer
      const int kn = (kt + 1) * 64;
      u16* bn = &sKV[(kt + 1) & 1][0][0];
      gload16(Kg + (size_t)kn * (2 * CC),      &bn[wb]);
      gload16(Kg + (size_t)kn * (2 * CC) + 32, &bn[TSZ + wb]);
      gload16(Vg + kn,                         &bn[2 * TSZ + wb]);
      gload16(Vg + kn + 32,                    &bn[3 * TSZ + wb]);
    }

    const u16* sK0 = &sKV[kt & 1][0][0];
    const u16* sK1 = &sKV[kt & 1][1][0];
    const u16* sV0 = &sKV[kt & 1][2][0];
    const u16* sV1 = &sKV[kt & 1][3][0];

    // S^T = K Q^T: frag j -> element (key = kt*64+j*16+qd*4+i, q = lr)
    floatx4 s[4] = {};
#pragma unroll
    for (int j = 0; j < 4; ++j) {
      bf16x8 kf0 = ld8(&sK0[(j * 16 + lr) * TS + qd * 8]);
      bf16x8 kf1 = ld8(&sK1[(j * 16 + lr) * TS + qd * 8]);
      s[j] = mfma16(kf0, qf0, s[j]);
      s[j] = mfma16(kf1, qf1, s[j]);
    }

    const bool diag = (kt == qtile);
    unsigned W[4][2];               // W[j][h]: bf16x2 of keys j*16+qd*4+2h+{0,1}
#pragma unroll
    for (int j = 0; j < 4; ++j) {
      float p[4];
#pragma unroll
      for (int i = 0; i < 4; ++i) {
        p[i] = __builtin_amdgcn_exp2f(s[j][i]);
        if (diag) {
          const int key = kt * 64 + j * 16 + qd * 4 + i;
          p[i] = (key <= myq) ? p[i] : 0.f;
        }
        lsum += p[i];
      }
      W[j][0] = __builtin_amdgcn_perm(__float_as_uint(p[1]), __float_as_uint(p[0]), 0x07060302);
      W[j][1] = __builtin_amdgcn_perm(__float_as_uint(p[3]), __float_as_uint(p[2]), 0x07060302);
    }

    uint4 F0, F1;
    qd_xchg(W[0][0], W[1][0], F0.x, F0.z);
    qd_xchg(W[0][1], W[1][1], F0.y, F0.w);
    qd_xchg(W[2][0], W[3][0], F1.x, F1.z);
    qd_xchg(W[2][1], W[3][1], F1.y, F1.w);
    const bf16x8 pf0 = __builtin_bit_cast(bf16x8, F0);
    const bf16x8 pf1 = __builtin_bit_cast(bf16x8, F1);

    // O += P V: D row = q (qd*4+i), col = dim (j*16+lr)
#pragma unroll
    for (int j = 0; j < 4; ++j) {
      bf16x8 vf0 = ld8(&sV0[(j * 16 + lr) * TS + qd * 8]);
      bf16x8 vf1 = ld8(&sV1[(j * 16 + lr) * TS + qd * 8]);
      o[j] = mfma16(pf0, vf0, o[j]);
      o[j] = mfma16(pf1, vf1, o[j]);
    }
    __syncthreads();   // drains kt+1 stage (vmcnt0) + protects buf reuse
  }

  lsum += __shfl_xor(lsum, 16);
  lsum += __shfl_xor(lsum, 32);
  float linv[4];
#pragma unroll
  for (int i = 0; i < 4; ++i) linv[i] = 1.0f / __shfl(lsum, qd * 4 + i);

#pragma unroll
  for (int j = 0; j < 4; ++j)
#pragma unroll
    for (int i = 0; i < 4; ++i) {
      const size_t row = (size_t)b * TT + q0 + w * 16 + qd * 4 + i;
      att[row * CC + h * HD + j * 16 + lr] = f2bf(o[j][i] * linv[i]);
    }
}

// ---------------------------------------------------------------------------
// ws layout (bytes):
//   xb   0        .. 16 MiB   bf16 [8192][1024]
//   waT  16 MiB   .. 22 MiB   bf16 [3072][1024]
//   wpT  22 MiB   .. 24 MiB   bf16 [1024][1024]
//   qk   24 MiB   .. 56 MiB   bf16 [8192][2048]   (Q|K, Q pre-scaled)
//   vT   56 MiB   .. 72 MiB   bf16 [4*1024][2048] (V^T per (b,dim))
//   att  72 MiB   .. 88 MiB   bf16 [8192][1024]
// ---------------------------------------------------------------------------
extern "C" void kernel_launch(void* const* d_in, const int* in_sizes, int n_in,
                              void* d_out, int out_size, void* d_ws, size_t ws_size,
                              hipStream_t stream) {
  const float* x      = (const float*)d_in[0];
  const float* w_attn = (const float*)d_in[1];
  const float* w_proj = (const float*)d_in[2];
  const float* b_proj = (const float*)d_in[3];
  float* out = (float*)d_out;

  char* ws = (char*)d_ws;
  u16* xb  = (u16*)(ws + 0);
  u16* waT = (u16*)(ws + 16777216);
  u16* wpT = (u16*)(ws + 23068672);
  u16* qk  = (u16*)(ws + 25165824);
  u16* vT  = (u16*)(ws + 58720256);
  u16* att = (u16*)(ws + 75497472);

  tobf16_kernel<<<8192, 256, 0, stream>>>((const float4*)x, (ushort4*)xb, 2097152);
  transpose_bf16_kernel<<<dim3(48, 16), 256, 0, stream>>>(w_attn, waT, CC, C3);
  transpose_bf16_kernel<<<dim3(16, 16), 256, 0, stream>>>(w_proj, wpT, CC, CC);

  // qkv = x @ w_attn  (M=8192, N=3072, K=1024) -> qk + vT
  // grid 24x32 = 768 blocks = 3 exact rounds at 1 block/CU
  gemm256_kernel<1><<<dim3(24, 32), 512, 0, stream>>>(xb, waT, nullptr, nullptr,
                                                      qk, vT, C3, CC);

  // attention: grid (bh, qtile) -> same-bh blocks share an XCD; LPT in y
  attn_kernel<<<dim3(64, 32), 256, 0, stream>>>(qk, vT, att);

  // out = att @ w_proj + b_proj  (M=8192, N=1024, K=1024), fp32 out
  // grid 8x32 = 256 blocks = exactly 1 round
  gemm256_kernel<2><<<dim3(8, 32), 512, 0, stream>>>(att, wpT, b_proj, out,
                                                     nullptr, nullptr, CC, CC);
}

// Round 8
// 219.885 us; speedup vs baseline: 1.0818x; 1.0576x over previous
//
#include <hip/hip_runtime.h>

// Problem constants
#define BB 4
#define TT 2048
#define CC 1024
#define C3 3072
#define HH 16
#define HD 64
#define BT 8192   // BB*TT

#define TS 32
#define TSZ (64 * TS)   // u16 elements per 64-row sub-tile (4 KB)

typedef __bf16 bf16x8 __attribute__((ext_vector_type(8)));
typedef float floatx4 __attribute__((ext_vector_type(4)));
typedef unsigned uintx2 __attribute__((ext_vector_type(2)));
typedef unsigned short u16;

__device__ __forceinline__ u16 f2bf(float f) {
  union { float f; unsigned u; } a; a.f = f;
  return (u16)((a.u + 0x7fffu + ((a.u >> 16) & 1u)) >> 16);  // RNE
}
__device__ __forceinline__ bf16x8 ld8(const u16* p) { return *(const bf16x8*)p; }
__device__ __forceinline__ floatx4 mfma16(bf16x8 a, bf16x8 b, floatx4 c) {
  return __builtin_amdgcn_mfma_f32_16x16x32_bf16(a, b, c, 0, 0, 0);
}

// Async global->LDS, 16B/lane. LDS dest = wave-uniform base + lane*16 (m104).
__device__ __forceinline__ void gload16(const u16* g, u16* l) {
  __builtin_amdgcn_global_load_lds(
      (const __attribute__((address_space(1))) void*)g,
      (__attribute__((address_space(3))) void*)l, 16, 0, 0);
}

// qd-group redistribution via permlane32/16_swap (verified R3):
//   r0 = [a@0, a@2, b@0, b@2], r1 = [a@1, a@3, b@1, b@3]  (by qd group)
__device__ __forceinline__ void qd_xchg(unsigned a, unsigned b,
                                        unsigned& r0, unsigned& r1) {
  uintx2 t = __builtin_amdgcn_permlane32_swap(a, b, false, false);
  uintx2 r = __builtin_amdgcn_permlane16_swap(t[0], t[1], false, false);
  r0 = r[0]; r1 = r[1];
}

// compiler-fence + hw barrier (no vmcnt drain, unlike __syncthreads)
#define BARR do { asm volatile("" ::: "memory"); \
                  __builtin_amdgcn_s_barrier(); \
                  asm volatile("" ::: "memory"); } while (0)
#define VMW4 asm volatile("s_waitcnt vmcnt(4)" ::: "memory")
#define VMW0 asm volatile("s_waitcnt vmcnt(0)" ::: "memory")

// ---------------------------------------------------------------------------
// R8: fused prep kernel (1 launch instead of 3; ~60 us of per-launch overhead
// observed across the pipeline, so kernel count matters).
//   blocks [0, 8192)        : fp32 -> bf16 for x (2M float4, exact fit)
//   blocks [8192, 8960)     : w_attn [1024][3072] -> waT [3072][1024] bf16
//   blocks [8960, 9216)     : w_proj [1024][1024] -> wpT [1024][1024] bf16
// Branches are block-uniform.  LDS 16.9 KB does not cut tobf16 occupancy
// (2048 thr/CU caps residency at 8 blocks regardless).
// ---------------------------------------------------------------------------
__global__ __launch_bounds__(256) void prep_kernel(
    const float4* __restrict__ x4, ushort4* __restrict__ xb4,
    const float* __restrict__ w_attn, u16* __restrict__ waT,
    const float* __restrict__ w_proj, u16* __restrict__ wpT) {
  __shared__ float s[64][65];
  const int t = threadIdx.x;
  const int bid = blockIdx.x;

  if (bid < 8192) {                 // --- tobf16 ---
    const int i = bid * 256 + t;    // 8192*256 == 2097152 exactly
    float4 v = x4[i];
    ushort4 o; o.x = f2bf(v.x); o.y = f2bf(v.y); o.z = f2bf(v.z); o.w = f2bf(v.w);
    xb4[i] = o;
    return;
  }

  // --- transpose fp32 [K][N] -> bf16 [N][K], 64x64 tile ---
  const float* src; u16* dst; int N, bx, by;
  if (bid < 8960) { const int b2 = bid - 8192; src = w_attn; dst = waT; N = C3;
                    bx = b2 % 48; by = b2 / 48; }
  else            { const int b2 = bid - 8960; src = w_proj; dst = wpT; N = CC;
                    bx = b2 % 16; by = b2 / 16; }
  const int K = CC;
  const int r = t >> 4;             // 0..15
  const int c = (t & 15) * 4;       // 0..60
  const int k0 = by * 64, n0 = bx * 64;
#pragma unroll
  for (int i = 0; i < 4; ++i) {
    float4 v = *(const float4*)&src[(size_t)(k0 + r + i * 16) * N + n0 + c];
    s[r + i * 16][c + 0] = v.x; s[r + i * 16][c + 1] = v.y;
    s[r + i * 16][c + 2] = v.z; s[r + i * 16][c + 3] = v.w;
  }
  __syncthreads();
#pragma unroll
  for (int i = 0; i < 4; ++i) {
    const int nn = r + i * 16;
    ushort4 o;
    o.x = f2bf(s[c + 0][nn]); o.y = f2bf(s[c + 1][nn]);
    o.z = f2bf(s[c + 2][nn]); o.w = f2bf(s[c + 3][nn]);
    *(ushort4*)&dst[(size_t)(n0 + nn) * K + k0 + c] = o;
  }
}

// ---------------------------------------------------------------------------
// R7: 256x128 4-phase GEMM, 512 thr = 8 waves (4M x 2N), 64x64 out per wave.
// Used for qkv ONLY (768 blocks = 3 rounds; multi-round grids amortize
// block->CU imbalance.  R7 lesson: a perfect-fit 1-round grid at 1 block/CU
// is fragile -- any CU that gets 2 blocks doubles the kernel time).
// LDS 96 KiB: lds[parity][ A 256x64 | B 128x64 ] u16, 16B-granular XOR
// swizzle LDS[row][c] = G[row][c ^ ((row&7)*8)] (inverse-swizzled global src
// on gload_lds + swizzled ds_read -> conflict-free; R6/R7 verified 459K/328K).
// Schedule (2 K-tiles per iter, 4 phases, 2 barriers/K-tile), slot-ring
// stages + counted vmcnt(4); last iter drains with vmcnt(0).
// MODE 1: qkv epilogue (Q pre-scaled 0.125*log2e; Q/K row bounce; V
//         transpose bounce -> vT).
// ---------------------------------------------------------------------------
template<int MODE>
__global__ __launch_bounds__(512, 2) void gemm256_kernel(
    const u16* __restrict__ A, const u16* __restrict__ B,
    const float* __restrict__ bias, float* __restrict__ outf,
    u16* __restrict__ qk, u16* __restrict__ vT, int N, int K) {
  __shared__ u16 lds[2][24576];   // [parity][A:0..16383 | B:16384..24575] 96 KiB

  const int t = threadIdx.x;      // 0..511
  const int lane = t & 63, lr = lane & 15, qd = lane >> 4;
  const int w = t >> 6, wm = w >> 1, wn = w & 1;
  const int m0 = blockIdx.y * 256, n0 = blockIdx.x * 128;

  const int srow = t >> 3;
  const int scol = ((t & 7) ^ (srow & 7)) * 8;   // u16
  const u16* Asrc = A + (size_t)(m0 + srow) * K + scol;
  const u16* Bsrc = B + (size_t)(n0 + srow) * K + scol;
  const int wvb = (t & ~63) * 8;                 // wave-uniform u16 base

  const int NT = K >> 6;          // 64-wide K-tiles (16)
  floatx4 acc[4][4] = {};

  const int abase = (wm * 64 + lr) * 64;
  const int bbase = (wn * 64 + lr) * 64;
  const int csw0 = (qd * 8) ^ ((lr & 7) * 8);
  const int csw1 = (32 + qd * 8) ^ ((lr & 7) * 8);

#define STG_A(PR, QA, TK) do { if ((TK) < NT) \
    gload16(Asrc + (size_t)((QA) * 64) * K + (TK) * 64, \
            &lds[PR][(QA) * 4096 + wvb]); } while (0)
#define STG_B(PR, HB, TK) do { if ((TK) < NT) \
    gload16(Bsrc + (size_t)((HB) * 64) * K + (TK) * 64, \
            &lds[PR][16384 + (HB) * 4096 + wvb]); } while (0)

  bf16x8 af[4][2], bf[2][2];
#define READ_A(PR) do { _Pragma("unroll") for (int mi = 0; mi < 4; ++mi) { \
    const u16* p_ = &lds[PR][mi * 1024 + abase]; \
    af[mi][0] = ld8(p_ + csw0); af[mi][1] = ld8(p_ + csw1); } } while (0)
#define READ_B(PR, NJ0) do { _Pragma("unroll") for (int nj = 0; nj < 2; ++nj) { \
    const u16* p_ = &lds[PR][16384 + ((NJ0) + nj) * 1024 + bbase]; \
    bf[nj][0] = ld8(p_ + csw0); bf[nj][1] = ld8(p_ + csw1); } } while (0)
#define MFMA16(NJ0) do { __builtin_amdgcn_s_setprio(1); _Pragma("unroll") \
    for (int mi = 0; mi < 4; ++mi) _Pragma("unroll") for (int nj = 0; nj < 2; ++nj) { \
      acc[mi][(NJ0) + nj] = mfma16(af[mi][0], bf[nj][0], acc[mi][(NJ0) + nj]); \
      acc[mi][(NJ0) + nj] = mfma16(af[mi][1], bf[nj][1], acc[mi][(NJ0) + nj]); } \
    __builtin_amdgcn_s_setprio(0); } while (0)

  // prologue: A(0),B(0) -> buf0; A(1) -> buf1.  vmcnt(4) leaves A(1) in flight.
  STG_A(0, 0, 0); STG_A(0, 1, 0); STG_A(0, 2, 0); STG_A(0, 3, 0);
  STG_B(0, 0, 0); STG_B(0, 1, 0);
  STG_A(1, 0, 1); STG_A(1, 1, 1); STG_A(1, 2, 1); STG_A(1, 3, 1);
  VMW4; BARR;

  const int NITER = NT >> 1;
  for (int it = 0; it < NITER; ++it) {
    const int T1 = 2 * it + 1, T2 = 2 * it + 2, T3 = 2 * it + 3;
    const bool last = (it == NITER - 1);
    // ph0: even tile (buf0) first half
    STG_B(1, 0, T1); STG_B(1, 1, T1);
    READ_A(0); READ_B(0, 0); MFMA16(0);
    BARR;
    // ph1: even tile second half (af reused)
    STG_A(0, 0, T2); STG_A(0, 1, T2); STG_A(0, 2, T2); STG_A(0, 3, T2);
    READ_B(0, 2); MFMA16(2);
    if (last) { VMW0; } else { VMW4; }
    BARR;
    // ph2: odd tile (buf1) first half
    STG_B(0, 0, T2); STG_B(0, 1, T2);
    READ_A(1); READ_B(1, 0); MFMA16(0);
    BARR;
    // ph3: odd tile second half
    STG_A(1, 0, T3); STG_A(1, 1, T3); STG_A(1, 2, T3); STG_A(1, 3, T3);
    READ_B(1, 2); MFMA16(2);
    if (last) { VMW0; } else { VMW4; }
    BARR;
  }
#undef STG_A
#undef STG_B
#undef READ_A
#undef READ_B
#undef MFMA16

  // ---- epilogue: all DMAs landed (vmcnt0 on last iter) + final barrier ----
  // D layout: col(N)=lane&15, row(M)=(lane>>4)*4+i  [m89/m91]
  u16* flat = &lds[0][0];
  if constexpr (MODE == 2) {
    const int rowg0 = m0 + wm * 64;
    const int colg0 = n0 + wn * 64;
#pragma unroll
    for (int nj = 0; nj < 4; ++nj) {
      const int col = colg0 + nj * 16 + lr;
      const float bv = bias[col];
#pragma unroll
      for (int mi = 0; mi < 4; ++mi)
#pragma unroll
        for (int i = 0; i < 4; ++i)
          outf[(size_t)(rowg0 + mi * 16 + qd * 4 + i) * N + col] = acc[mi][nj][i] + bv;
    }
  } else {
    const bool isV = (n0 >= 2 * CC);   // block-uniform
    if (!isV) {
      const float qs = (n0 < CC) ? 0.18033688011f : 1.0f;
      u16* Tw = flat + w * (32 * 72);  // per-wave [32 rows][72]
      const int C0 = n0 + wn * 64;
#pragma unroll
      for (int mi2 = 0; mi2 < 2; ++mi2) {
#pragma unroll
        for (int mh = 0; mh < 2; ++mh)
#pragma unroll
          for (int nj = 0; nj < 4; ++nj)
#pragma unroll
            for (int i = 0; i < 4; ++i)
              Tw[(mh * 16 + qd * 4 + i) * 72 + nj * 16 + lr] =
                  f2bf(acc[mi2 * 2 + mh][nj][i] * qs);
        const int R0 = m0 + wm * 64 + mi2 * 32;
#pragma unroll
        for (int s = 0; s < 4; ++s) {
          const int rl = s * 8 + (lane >> 3);
          const int c0 = (lane & 7) * 8;
          *(bf16x8*)&qk[(size_t)(R0 + rl) * (2 * CC) + C0 + c0] =
              ld8(&Tw[rl * 72 + c0]);
        }
      }
    } else {
      u16* Tv = flat + w * (64 * 72);  // per-wave [64 dims][72]
      const int bI = m0 >> 11;
      const int tbase = (m0 & (TT - 1)) + wm * 64;
      const int dim0 = (n0 - 2 * CC) + wn * 64;
#pragma unroll
      for (int nj = 0; nj < 4; ++nj)
#pragma unroll
        for (int mi = 0; mi < 4; ++mi)
#pragma unroll
          for (int i = 0; i < 4; ++i)
            Tv[(nj * 16 + lr) * 72 + mi * 16 + qd * 4 + i] =
                f2bf(acc[mi][nj][i]);
#pragma unroll
      for (int s = 0; s < 8; ++s) {
        const int dl = s * 8 + (lane >> 3);
        const int t0 = (lane & 7) * 8;
        *(bf16x8*)&vT[((size_t)(bI << 10) + dim0 + dl) * TT + tbase + t0] =
            ld8(&Tv[dl * 72 + t0]);
      }
    }
  }
}

// ---------------------------------------------------------------------------
// 128x128 GEMM, BK=32, 256 thr = 4 waves.  global_load_lds staging; one
// barrier per K-iter (R4, verified).  Used for proj: 512 blocks, 32 KB LDS,
// ~4-5 resident blocks/CU -> self-balancing (R7 lesson).
// fp32 out + bias, direct stores.
// ---------------------------------------------------------------------------
template<int MODE>
__global__ __launch_bounds__(256) void gemm_kernel(
    const u16* __restrict__ A, const u16* __restrict__ B,
    const float* __restrict__ bias, float* __restrict__ outf,
    int M, int N, int K) {
  __shared__ u16 smem[2][2][2 * TSZ];   // [buf][A|B][128 rows x TS] = 32 KB

  const int t = threadIdx.x;
  const int w = t >> 6, lane = t & 63, lr = lane & 15, qd = lane >> 4;
  const int wm = w >> 1, wn = w & 1;
  const int m0 = blockIdx.y * 128, n0 = blockIdx.x * 128;

  const int sr = t >> 2;
  const int sc = (t & 3) * 8;
  const int wb = (t & ~63) * 8;
  const u16* Ag = A + (size_t)(m0 + sr) * K + sc;
  const u16* Bg = B + (size_t)(n0 + sr) * K + sc;

  floatx4 acc[4][4] = {};

  {  // prologue: stage tile 0 into buf 0
    u16* sA = &smem[0][0][0];
    u16* sB = &smem[0][1][0];
    gload16(Ag,                  &sA[wb]);
    gload16(Ag + (size_t)64 * K, &sA[TSZ + wb]);
    gload16(Bg,                  &sB[wb]);
    gload16(Bg + (size_t)64 * K, &sB[TSZ + wb]);
  }
  __syncthreads();

  for (int k0 = 0; k0 < K; k0 += 32) {
    const int p = (k0 >> 5) & 1;
    if (k0 + 32 < K) {               // stage next tile into the OTHER buffer
      u16* sA = &smem[p ^ 1][0][0];
      u16* sB = &smem[p ^ 1][1][0];
      gload16(Ag + k0 + 32,                  &sA[wb]);
      gload16(Ag + (size_t)64 * K + k0 + 32, &sA[TSZ + wb]);
      gload16(Bg + k0 + 32,                  &sB[wb]);
      gload16(Bg + (size_t)64 * K + k0 + 32, &sB[TSZ + wb]);
    }
    const u16* sA = &smem[p][0][0];
    const u16* sB = &smem[p][1][0];

    bf16x8 af[4], bf[4];
#pragma unroll
    for (int mj = 0; mj < 4; ++mj) af[mj] = ld8(&sA[(wm * 64 + mj * 16 + lr) * TS + qd * 8]);
#pragma unroll
    for (int nj = 0; nj < 4; ++nj) bf[nj] = ld8(&sB[(wn * 64 + nj * 16 + lr) * TS + qd * 8]);
#pragma unroll
    for (int mj = 0; mj < 4; ++mj)
#pragma unroll
      for (int nj = 0; nj < 4; ++nj)
        acc[mj][nj] = mfma16(af[mj], bf[nj], acc[mj][nj]);
    __syncthreads();   // drains next-tile stage (vmcnt0) + protects buf reuse
  }

  // Epilogue. D layout: col(N)=lane&15, row(M)=(lane>>4)*4+i  [m89/m91]
  const int rowg0 = m0 + wm * 64;
  const int colg0 = n0 + wn * 64;
#pragma unroll
  for (int nj = 0; nj < 4; ++nj) {
    const int col = colg0 + nj * 16 + lr;
    const float bv = bias[col];
#pragma unroll
    for (int mj = 0; mj < 4; ++mj)
#pragma unroll
      for (int i = 0; i < 4; ++i)
        outf[(size_t)(rowg0 + mj * 16 + qd * 4 + i) * N + col] = acc[mj][nj][i] + bv;
  }
}

// ---------------------------------------------------------------------------
// Causal flash attention (R4 version).  Wave = 16 q, block = 64 q.  K/V
// staging via global_load_lds, one barrier per kt.  In-register P via
// permlane (R3).  Q pre-scaled by 0.125*log2e.
// ---------------------------------------------------------------------------
__global__ __launch_bounds__(256, 5) void attn_kernel(const u16* __restrict__ qk,
                                                      const u16* __restrict__ vT,
                                                      u16* __restrict__ att) {
  __shared__ u16 sKV[2][4][TSZ];      // [buf][K0,K1,V0,V1] = 32768 B

  const int t = threadIdx.x;
  const int w = t >> 6, lane = t & 63, lr = lane & 15, qd = lane >> 4;
  const int qtile = 31 - blockIdx.y;  // LPT: longest first
  const int bh = blockIdx.x;          // x fastest -> XCD = bh % 8 for all qtiles
  const int b = bh >> 4, h = bh & 15;
  const int q0 = qtile * 64;
  const u16* qbase = qk + (size_t)b * TT * (2 * CC);

  const u16* qp = qbase + (size_t)(q0 + w * 16 + lr) * (2 * CC) + h * HD;
  const bf16x8 qf0 = ld8(qp + qd * 8);
  const bf16x8 qf1 = ld8(qp + 32 + qd * 8);

  const int sr = t >> 2, sc = (t & 3) * 8;
  const int wb = (t & ~63) * 8;   // wave-uniform u16 base within a sub-tile
  const u16* Kg = qbase + (size_t)sr * (2 * CC) + CC + h * HD + sc;
  const u16* Vg = vT + ((size_t)bh * HD + sr) * TT + sc;

  float lsum = 0.f;                 // per-lane partial: q = lr
  floatx4 o[4] = {};
  const int myq = q0 + w * 16 + lr;

  {  // prologue: stage tile 0 into buf 0
    u16* b0 = &sKV[0][0][0];
    gload16(Kg,      &b0[wb]);
    gload16(Kg + 32, &b0[TSZ + wb]);
    gload16(Vg,      &b0[2 * TSZ + wb]);
    gload16(Vg + 32, &b0[3 * TSZ + wb]);
  }
  __syncthreads();

  for (int kt = 0; kt <= qtile; ++kt) {
    if (kt < qtile) {               // stage kt+1 into the OTHER buffer
      const int kn = (kt + 1) * 64;
      u16* bn = &sKV[(kt + 1) & 1][0][0];
      gload16(Kg + (size_t)kn * (2 * CC),      &bn[wb]);
      gload16(Kg + (size_t)kn * (2 * CC) + 32, &bn[TSZ + wb]);
      gload16(Vg + kn,                         &bn[2 * TSZ + wb]);
      gload16(Vg + kn + 32,                    &bn[3 * TSZ + wb]);
    }

    const u16* sK0 = &sKV[kt & 1][0][0];
    const u16* sK1 = &sKV[kt & 1][1][0];
    const u16* sV0 = &sKV[kt & 1][2][0];
    const u16* sV1 = &sKV[kt & 1][3][0];

    // S^T = K Q^T: frag j -> element (key = kt*64+j*16+qd*4+i, q = lr)
    floatx4 s[4] = {};
#pragma unroll
    for (int j = 0; j < 4; ++j) {
      bf16x8 kf0 = ld8(&sK0[(j * 16 + lr) * TS + qd * 8]);
      bf16x8 kf1 = ld8(&sK1[(j * 16 + lr) * TS + qd * 8]);
      s[j] = mfma16(kf0, qf0, s[j]);
      s[j] = mfma16(kf1, qf1, s[j]);
    }

    const bool diag = (kt == qtile);
    unsigned W[4][2];               // W[j][h]: bf16x2 of keys j*16+qd*4+2h+{0,1}
#pragma unroll
    for (int j = 0; j < 4; ++j) {
      float p[4];
#pragma unroll
      for (int i = 0; i < 4; ++i) {
        p[i] = __builtin_amdgcn_exp2f(s[j][i]);
        if (diag) {
          const int key = kt * 64 + j * 16 + qd * 4 + i;
          p[i] = (key <= myq) ? p[i] : 0.f;
        }
        lsum += p[i];
      }
      W[j][0] = __builtin_amdgcn_perm(__float_as_uint(p[1]), __float_as_uint(p[0]), 0x07060302);
      W[j][1] = __builtin_amdgcn_perm(__float_as_uint(p[3]), __float_as_uint(p[2]), 0x07060302);
    }

    uint4 F0, F1;
    qd_xchg(W[0][0], W[1][0], F0.x, F0.z);
    qd_xchg(W[0][1], W[1][1], F0.y, F0.w);
    qd_xchg(W[2][0], W[3][0], F1.x, F1.z);
    qd_xchg(W[2][1], W[3][1], F1.y, F1.w);
    const bf16x8 pf0 = __builtin_bit_cast(bf16x8, F0);
    const bf16x8 pf1 = __builtin_bit_cast(bf16x8, F1);

    // O += P V: D row = q (qd*4+i), col = dim (j*16+lr)
#pragma unroll
    for (int j = 0; j < 4; ++j) {
      bf16x8 vf0 = ld8(&sV0[(j * 16 + lr) * TS + qd * 8]);
      bf16x8 vf1 = ld8(&sV1[(j * 16 + lr) * TS + qd * 8]);
      o[j] = mfma16(pf0, vf0, o[j]);
      o[j] = mfma16(pf1, vf1, o[j]);
    }
    __syncthreads();   // drains kt+1 stage (vmcnt0) + protects buf reuse
  }

  lsum += __shfl_xor(lsum, 16);
  lsum += __shfl_xor(lsum, 32);
  float linv[4];
#pragma unroll
  for (int i = 0; i < 4; ++i) linv[i] = 1.0f / __shfl(lsum, qd * 4 + i);

#pragma unroll
  for (int j = 0; j < 4; ++j)
#pragma unroll
    for (int i = 0; i < 4; ++i) {
      const size_t row = (size_t)b * TT + q0 + w * 16 + qd * 4 + i;
      att[row * CC + h * HD + j * 16 + lr] = f2bf(o[j][i] * linv[i]);
    }
}

// ---------------------------------------------------------------------------
// ws layout (bytes):
//   xb   0        .. 16 MiB   bf16 [8192][1024]
//   waT  16 MiB   .. 22 MiB   bf16 [3072][1024]
//   wpT  22 MiB   .. 24 MiB   bf16 [1024][1024]
//   qk   24 MiB   .. 56 MiB   bf16 [8192][2048]   (Q|K, Q pre-scaled)
//   vT   56 MiB   .. 72 MiB   bf16 [4*1024][2048] (V^T per (b,dim))
//   att  72 MiB   .. 88 MiB   bf16 [8192][1024]
// ---------------------------------------------------------------------------
extern "C" void kernel_launch(void* const* d_in, const int* in_sizes, int n_in,
                              void* d_out, int out_size, void* d_ws, size_t ws_size,
                              hipStream_t stream) {
  const float* x      = (const float*)d_in[0];
  const float* w_attn = (const float*)d_in[1];
  const float* w_proj = (const float*)d_in[2];
  const float* b_proj = (const float*)d_in[3];
  float* out = (float*)d_out;

  char* ws = (char*)d_ws;
  u16* xb  = (u16*)(ws + 0);
  u16* waT = (u16*)(ws + 16777216);
  u16* wpT = (u16*)(ws + 23068672);
  u16* qk  = (u16*)(ws + 25165824);
  u16* vT  = (u16*)(ws + 58720256);
  u16* att = (u16*)(ws + 75497472);

  // fused prep: tobf16 (8192 blocks) + w_attn^T (768) + w_proj^T (256)
  prep_kernel<<<9216, 256, 0, stream>>>((const float4*)x, (ushort4*)xb,
                                        w_attn, waT, w_proj, wpT);

  // qkv = x @ w_attn  (M=8192, N=3072, K=1024) -> qk + vT
  // grid 24x32 = 768 blocks = 3 rounds (amortizes block->CU imbalance)
  gemm256_kernel<1><<<dim3(24, 32), 512, 0, stream>>>(xb, waT, nullptr, nullptr,
                                                      qk, vT, C3, CC);

  // attention: grid (bh, qtile) -> same-bh blocks share an XCD; LPT in y
  attn_kernel<<<dim3(64, 32), 256, 0, stream>>>(qk, vT, att);

  // out = att @ w_proj + b_proj  (M=8192, N=1024, K=1024), fp32 out
  // 128^2 tiles: 512 blocks, ~4-5 resident/CU, self-balancing
  gemm_kernel<2><<<dim3(8, 64), 256, 0, stream>>>(att, wpT, b_proj, out,
                                                  BT, CC, CC);
}